// Round 8
// baseline (253.909 us; speedup 1.0000x reference)
//
#include <hip/hip_runtime.h>
#include <math.h>

#define B_ 128
#define INPUT_ 128
#define N_ 4096
#define M_ 128
#define H_ 512
#define OUT_ 128
#define EPS_ 1e-8f

typedef float f4v __attribute__((ext_vector_type(4)));

// ---- d_out layout (float element offsets, reference return order) ----
#define OUT_OFF    0
#define RV_OUT_OFF 16384
#define H_OFF      32768
#define C_OFF      98304
#define RW_OFF     163840
#define WW_OFF     688128
#define NM_OFF     1212416

// ---- workspace layout (float element offsets) ----
#define KR_OFF     0
#define KW_OFF     16384
#define E_OFF      32768
#define A_OFF      49152
#define PRR_OFF    65536
#define PRW_OFF    66560
#define SIMR_OFF   67584
#define SIMW_OFF   591872
#define RVACC_OFF  1116160
#define PART_OFF   1132544   // k1 partials [8][2048][128]; k2 partials [4][128][576]; k5 rv partials [128][64][128]

#define KSPLIT 8
#define KPER   96
#define BO     64

#define J_FULL 524
#define J_PAD  576
#define KS2    4

#define GRP    64            // batches per group: 128 MB slice, L3-resident between k3(g) and k5(g)

__device__ __forceinline__ float sigmoidf_(float x){ return 1.0f/(1.0f+expf(-x)); }
__device__ __forceinline__ float softplusf_(float x){ return fmaxf(x,0.0f) + log1pf(expf(-fabsf(x))); }

// ---------------- K1a: gates GEMM, split-K tiled f32 ----------------
__global__ __launch_bounds__(256) void k1a_gemm(
    const float* __restrict__ inp, const float* __restrict__ prev_reads,
    const float* __restrict__ h_prev,
    const float* __restrict__ W_ih, const float* __restrict__ W_hh,
    float* __restrict__ part)   // [KSPLIT][2048][128]
{
  __shared__ float wt[32*68];
  __shared__ float xs[32*128];
  int t = threadIdx.x;
  int O0 = blockIdx.x * BO;
  int ks = blockIdx.y;
  int oq = t >> 5, bq = t & 31;
  float acc[8][4];
  #pragma unroll
  for (int i=0;i<8;++i)
    #pragma unroll
    for (int c=0;c<4;++c) acc[i][c]=0.f;

  for (int st = 0; st < 3; ++st) {
    int kg0 = ks*KPER + st*32;
    __syncthreads();
    {
      int o = t >> 2, kq = t & 3;
      int j = O0 + o;
      const float* wsrc; int col;
      if (kg0 < 256) { wsrc = W_ih + (size_t)j*256; col = kg0; }
      else           { wsrc = W_hh + (size_t)j*512; col = kg0 - 256; }
      float4 a0 = *(const float4*)(wsrc + col + kq*8);
      float4 a1 = *(const float4*)(wsrc + col + kq*8 + 4);
      int kk = kq*8;
      wt[(kk+0)*68+o]=a0.x; wt[(kk+1)*68+o]=a0.y; wt[(kk+2)*68+o]=a0.z; wt[(kk+3)*68+o]=a0.w;
      wt[(kk+4)*68+o]=a1.x; wt[(kk+5)*68+o]=a1.y; wt[(kk+6)*68+o]=a1.z; wt[(kk+7)*68+o]=a1.w;
    }
    {
      int b = t >> 1, kq = t & 1;
      const float* src; int col;
      if (kg0 < 128)      { src = inp        + (size_t)b*128; col = kg0; }
      else if (kg0 < 256) { src = prev_reads + (size_t)b*128; col = kg0-128; }
      else                { src = h_prev     + (size_t)b*512; col = kg0-256; }
      #pragma unroll
      for (int r = 0; r < 4; ++r) {
        float4 v = *(const float4*)(src + col + kq*16 + r*4);
        int kk = kq*16 + r*4;
        xs[(kk+0)*128+b]=v.x; xs[(kk+1)*128+b]=v.y; xs[(kk+2)*128+b]=v.z; xs[(kk+3)*128+b]=v.w;
      }
    }
    __syncthreads();
    #pragma unroll
    for (int kk = 0; kk < 32; ++kk) {
      float4 wa = *(const float4*)&wt[kk*68 + oq*8];
      float4 wb = *(const float4*)&wt[kk*68 + oq*8 + 4];
      float4 xv = *(const float4*)&xs[kk*128 + bq*4];
      float wv[8] = {wa.x,wa.y,wa.z,wa.w,wb.x,wb.y,wb.z,wb.w};
      float xx[4] = {xv.x,xv.y,xv.z,xv.w};
      #pragma unroll
      for (int i=0;i<8;++i)
        #pragma unroll
        for (int c=0;c<4;++c)
          acc[i][c] += wv[i]*xx[c];
    }
  }
  #pragma unroll
  for (int i=0;i<8;++i) {
    int j = O0 + oq*8 + i;
    float4 v = make_float4(acc[i][0],acc[i][1],acc[i][2],acc[i][3]);
    *(float4*)(part + ((size_t)ks*2048 + j)*128 + bq*4) = v;
  }
}

// ---------------- K1b: reduce split-K partials + LSTM activations ----------------
__global__ __launch_bounds__(128) void k1b_act(
    const float* __restrict__ part, const float* __restrict__ c_prev,
    const float* __restrict__ b_ih, const float* __restrict__ b_hh,
    float* __restrict__ h_out, float* __restrict__ c_out)
{
  int u = blockIdx.x;
  int b = threadIdx.x;
  float g[4];
  #pragma unroll
  for (int q=0;q<4;++q) {
    int j = q*H_ + u;
    float s = b_ih[j] + b_hh[j];
    #pragma unroll
    for (int ksp=0;ksp<KSPLIT;++ksp)
      s += part[((size_t)ksp*2048 + j)*128 + b];
    g[q] = s;
  }
  float ig = sigmoidf_(g[0]), fg = sigmoidf_(g[1]);
  float gg = tanhf(g[2]),     og = sigmoidf_(g[3]);
  float cn = fg * c_prev[(size_t)b*H_ + u] + ig*gg;
  float hn = og * tanhf(cn);
  c_out[(size_t)b*H_ + u] = cn;
  h_out[(size_t)b*H_ + u] = hn;
}

// ---------------- K2a: projection GEMM (read_W ++ write_W), split-K ----------------
__global__ __launch_bounds__(256) void k2a_gemm(
    const float* __restrict__ h,
    const float* __restrict__ read_W, const float* __restrict__ write_W,
    float* __restrict__ part)  // [KS2][128][J_PAD]
{
  __shared__ float wt[32*68];
  __shared__ float xs[32*128];
  int t = threadIdx.x;
  int j0 = blockIdx.x * 64;
  int ks = blockIdx.y;
  int jq = t >> 5, bq = t & 31;
  float acc[8][4];
  #pragma unroll
  for (int i=0;i<8;++i)
    #pragma unroll
    for (int c=0;c<4;++c) acc[i][c]=0.f;

  for (int st = 0; st < 4; ++st) {
    int k0 = ks*128 + st*32;
    __syncthreads();
    for (int e = t; e < 32*64; e += 256) {
      int kk = e >> 6, j = e & 63;
      int jc = j0 + j;
      int u = k0 + kk;
      float v = 0.f;
      if (jc < 134)          v = read_W[(size_t)u*134 + jc];
      else if (jc < J_FULL)  v = write_W[(size_t)u*390 + (jc-134)];
      wt[kk*68 + j] = v;
    }
    {
      int b = t >> 1, kq = t & 1;
      const float* src = h + (size_t)b*512 + k0 + kq*16;
      #pragma unroll
      for (int r = 0; r < 4; ++r) {
        float4 v = *(const float4*)(src + r*4);
        int kk = kq*16 + r*4;
        xs[(kk+0)*128+b]=v.x; xs[(kk+1)*128+b]=v.y; xs[(kk+2)*128+b]=v.z; xs[(kk+3)*128+b]=v.w;
      }
    }
    __syncthreads();
    #pragma unroll
    for (int kk = 0; kk < 32; ++kk) {
      float4 wa = *(const float4*)&wt[kk*68 + jq*8];
      float4 wb = *(const float4*)&wt[kk*68 + jq*8 + 4];
      float4 xv = *(const float4*)&xs[kk*128 + bq*4];
      float wv[8] = {wa.x,wa.y,wa.z,wa.w,wb.x,wb.y,wb.z,wb.w};
      float xx[4] = {xv.x,xv.y,xv.z,xv.w};
      #pragma unroll
      for (int i=0;i<8;++i)
        #pragma unroll
        for (int c=0;c<4;++c)
          acc[i][c] += wv[i]*xx[c];
    }
  }
  #pragma unroll
  for (int c=0;c<4;++c) {
    int b = bq*4 + c;
    float4 v0 = make_float4(acc[0][c],acc[1][c],acc[2][c],acc[3][c]);
    float4 v1 = make_float4(acc[4][c],acc[5][c],acc[6][c],acc[7][c]);
    *(float4*)(part + ((size_t)ks*128 + b)*J_PAD + j0 + jq*8)     = v0;
    *(float4*)(part + ((size_t)ks*128 + b)*J_PAD + j0 + jq*8 + 4) = v1;
  }
}

// ---------------- K2b: reduce partials + split_addr ----------------
__global__ __launch_bounds__(256) void k2b_post(
    const float* __restrict__ part,
    const float* __restrict__ read_b, const float* __restrict__ write_b,
    float* __restrict__ ws)
{
  int b = blockIdx.x, t = threadIdx.x;
  __shared__ float raw[J_FULL];
  __shared__ float red[128];
  for (int j = t; j < J_FULL; j += 256) {
    float s = (j < 134) ? read_b[j] : write_b[j-134];
    #pragma unroll
    for (int ks = 0; ks < KS2; ++ks)
      s += part[((size_t)ks*128 + b)*J_PAD + j];
    raw[j] = s;
  }
  __syncthreads();
  float krv = 0.f, kwv = 0.f;
  if (t < 128) {
    krv = tanhf(raw[t]);
    kwv = tanhf(raw[134+t]);
    ws[KR_OFF + b*M_ + t] = krv;
    ws[KW_OFF + b*M_ + t] = kwv;
    ws[E_OFF  + b*M_ + t] = sigmoidf_(raw[268+t]);
    ws[A_OFF  + b*M_ + t] = tanhf(raw[396+t]);
  }
  if (t < 128) red[t] = krv*krv;
  __syncthreads();
  for (int s = 64; s > 0; s >>= 1) { if (t < s) red[t] += red[t+s]; __syncthreads(); }
  float nr = sqrtf(red[0]);
  __syncthreads();
  if (t < 128) red[t] = kwv*kwv;
  __syncthreads();
  for (int s = 64; s > 0; s >>= 1) { if (t < s) red[t] += red[t+s]; __syncthreads(); }
  float nw = sqrtf(red[0]);
  if (t == 0) {
    float beta = softplusf_(raw[128]);
    float g    = sigmoidf_(raw[129]);
    float s0 = raw[130], s1 = raw[131], s2 = raw[132];
    float mx = fmaxf(s0, fmaxf(s1, s2));
    float e0 = expf(s0-mx), e1 = expf(s1-mx), e2 = expf(s2-mx);
    float es = e0+e1+e2;
    float gamma = 1.0f + softplusf_(raw[133]);
    float* pr = ws + PRR_OFF + b*8;
    pr[0]=beta; pr[1]=g; pr[2]=gamma; pr[3]=e0/es; pr[4]=e1/es; pr[5]=e2/es; pr[6]=nr;
  }
  if (t == 1) {
    float beta = softplusf_(raw[262]);
    float g    = sigmoidf_(raw[263]);
    float s0 = raw[264], s1 = raw[265], s2 = raw[266];
    float mx = fmaxf(s0, fmaxf(s1, s2));
    float e0 = expf(s0-mx), e1 = expf(s1-mx), e2 = expf(s2-mx);
    float es = e0+e1+e2;
    float gamma = 1.0f + softplusf_(raw[267]);
    float* pr = ws + PRW_OFF + b*8;
    pr[0]=beta; pr[1]=g; pr[2]=gamma; pr[3]=e0/es; pr[4]=e1/es; pr[5]=e2/es; pr[6]=nw;
  }
}

// ---------------- K3: cosine similarity pass over one batch-group ----------------
__global__ __launch_bounds__(256) void k3_sim(const float* __restrict__ memory,
                                              float* __restrict__ ws, int b0)
{
  int b = b0 + blockIdx.y, t = threadIdx.x;
  int n0 = blockIdx.x * 64;
  __shared__ float skr[128], skw[128];
  if (t < 128) { skr[t] = ws[KR_OFF + b*M_ + t]; skw[t] = ws[KW_OFF + b*M_ + t]; }
  __syncthreads();
  float knr = ws[PRR_OFF + b*8 + 6];
  float knw = ws[PRW_OFF + b*8 + 6];
  int wave = t >> 6, lane = t & 63, half = lane >> 5, l32 = lane & 31;
  int m0 = l32 * 4;
  #pragma unroll
  for (int i = 0; i < 8; ++i) {
    int n = n0 + i*8 + wave*2 + half;
    const float4* row = (const float4*)(memory + ((size_t)b*N_ + n)*M_);
    float4 v = row[l32];
    float dr = v.x*skr[m0] + v.y*skr[m0+1] + v.z*skr[m0+2] + v.w*skr[m0+3];
    float dw = v.x*skw[m0] + v.y*skw[m0+1] + v.z*skw[m0+2] + v.w*skw[m0+3];
    float ss = v.x*v.x + v.y*v.y + v.z*v.z + v.w*v.w;
    #pragma unroll
    for (int msk = 16; msk >= 1; msk >>= 1) {
      dr += __shfl_xor(dr, msk, 64);
      dw += __shfl_xor(dw, msk, 64);
      ss += __shfl_xor(ss, msk, 64);
    }
    if (l32 == 0) {
      float nm = sqrtf(ss);
      ws[SIMR_OFF + (size_t)b*N_ + n] = dr / (nm*knr + EPS_);
      ws[SIMW_OFF + (size_t)b*N_ + n] = dw / (nm*knw + EPS_);
    }
  }
}

// ---------------- K4: softmax + interpolate + shift + sharpen (one group) ----------------
__global__ __launch_bounds__(512) void k4_addr(
    const float* __restrict__ prev_rw, const float* __restrict__ prev_ww,
    float* __restrict__ ws, float* __restrict__ d_out, int b0)
{
  int which = blockIdx.x, b = b0 + blockIdx.y, t = threadIdx.x;
  int wid = t >> 6, lane = t & 63;
  const float* sim  = ws + (which ? SIMW_OFF : SIMR_OFF) + (size_t)b*N_;
  const float* prev = (which ? prev_ww : prev_rw) + (size_t)b*N_;
  const float* pr   = ws + (which ? PRW_OFF : PRR_OFF) + b*8;
  float* outw = d_out + (which ? WW_OFF : RW_OFF) + (size_t)b*N_;
  float beta = pr[0], g = pr[1], gamma = pr[2], s0 = pr[3], s1 = pr[4], s2 = pr[5];

  __shared__ float w[N_];
  __shared__ float redmax[8], redsum[8], redp[8];

  float vv[8];
  float mx = -1e30f;
  #pragma unroll
  for (int k = 0; k < 8; ++k) {
    int i = t + k*512;
    float v = beta * sim[i];
    vv[k] = v;
    mx = fmaxf(mx, v);
  }
  #pragma unroll
  for (int m = 1; m <= 32; m <<= 1) mx = fmaxf(mx, __shfl_xor(mx, m, 64));
  if (lane == 0) redmax[wid] = mx;
  __syncthreads();
  mx = redmax[0];
  #pragma unroll
  for (int j = 1; j < 8; ++j) mx = fmaxf(mx, redmax[j]);

  float sum = 0.f;
  #pragma unroll
  for (int k = 0; k < 8; ++k) {
    float v = __expf(vv[k] - mx);
    vv[k] = v;
    sum += v;
  }
  #pragma unroll
  for (int m = 1; m <= 32; m <<= 1) sum += __shfl_xor(sum, m, 64);
  if (lane == 0) redsum[wid] = sum;
  __syncthreads();
  sum = 0.f;
  #pragma unroll
  for (int j = 0; j < 8; ++j) sum += redsum[j];
  float inv = 1.0f / sum;

  #pragma unroll
  for (int k = 0; k < 8; ++k) {
    int i = t + k*512;
    w[i] = g * vv[k] * inv + (1.0f - g) * prev[i];
  }
  __syncthreads();

  float p[8]; float psum = 0.f;
  #pragma unroll
  for (int k = 0; k < 8; ++k) {
    int i = t + k*512;
    float wt = s0 * w[(i-1)&(N_-1)] + s1 * w[i] + s2 * w[(i+1)&(N_-1)];
    float v = __expf(gamma * __logf(wt + EPS_));
    p[k] = v; psum += v;
  }
  #pragma unroll
  for (int m = 1; m <= 32; m <<= 1) psum += __shfl_xor(psum, m, 64);
  if (lane == 0) redp[wid] = psum;
  __syncthreads();
  psum = 0.f;
  #pragma unroll
  for (int j = 0; j < 8; ++j) psum += redp[j];
  float pinv = 1.0f / psum;
  #pragma unroll
  for (int k = 0; k < 8; ++k) {
    int i = t + k*512;
    outw[i] = p[k] * pinv;
  }
}

// ---------------- K5: read_vec partials + memory erase/add (one group) ----------------
// Same (b,tile) order as k3(g): the group slice was just streamed, so normal
// (allocating) loads hit L3. NT stores keep the write stream from evicting it.
__global__ __launch_bounds__(256) void k5_update(
    const float* __restrict__ memory, float* __restrict__ d_out,
    float* __restrict__ ws, float* __restrict__ rvp, int b0)
{
  int b = b0 + blockIdx.y;
  int tx = blockIdx.x;
  int t = threadIdx.x;
  int n0 = tx * 64;
  __shared__ float se[128], sa[128];
  __shared__ float rvsh[8][128];
  if (t < 128) {
    se[t] = ws[E_OFF + b*M_ + t];
    sa[t] = ws[A_OFF + b*M_ + t];
  }
  __syncthreads();
  const float* rw  = d_out + RW_OFF + (size_t)b*N_;
  const float* wwp = d_out + WW_OFF + (size_t)b*N_;
  float* nm = d_out + NM_OFF;
  int wave = t >> 6, lane = t & 63, half = lane >> 5, l32 = lane & 31;
  int slot = wave*2 + half;
  int m0 = l32 * 4;
  float rx = 0.f, ry = 0.f, rz = 0.f, rw4 = 0.f;
  #pragma unroll
  for (int i = 0; i < 8; ++i) {
    int n = n0 + i*8 + slot;
    size_t off = ((size_t)b*N_ + n) * M_;
    float4 v = ((const float4*)(memory + off))[l32];
    float rwn = rw[n], wwn = wwp[n];
    rx += rwn*v.x; ry += rwn*v.y; rz += rwn*v.z; rw4 += rwn*v.w;
    f4v o;
    o.x = v.x * (1.0f - wwn*se[m0+0]) + wwn*sa[m0+0];
    o.y = v.y * (1.0f - wwn*se[m0+1]) + wwn*sa[m0+1];
    o.z = v.z * (1.0f - wwn*se[m0+2]) + wwn*sa[m0+2];
    o.w = v.w * (1.0f - wwn*se[m0+3]) + wwn*sa[m0+3];
    __builtin_nontemporal_store(o, (f4v*)(nm + off) + l32);
  }
  rvsh[slot][m0+0] = rx;
  rvsh[slot][m0+1] = ry;
  rvsh[slot][m0+2] = rz;
  rvsh[slot][m0+3] = rw4;
  __syncthreads();
  if (t < 128) {
    float s = 0.f;
    #pragma unroll
    for (int j = 0; j < 8; ++j) s += rvsh[j][t];
    rvp[((size_t)b*64 + tx)*128 + t] = s;
  }
}

// ---------------- K6: reduce rv partials + FC head (4 batches/block) ----------------
__global__ __launch_bounds__(128) void k6_fc(
    const float* __restrict__ fc_W, const float* __restrict__ fc_b,
    float* __restrict__ d_out, const float* __restrict__ rvp)
{
  int b0 = blockIdx.x * 4, t = threadIdx.x;
  __shared__ float xh[4][H_ + M_];
  #pragma unroll
  for (int q = 0; q < 4; ++q)
    for (int i = t; i < H_; i += 128)
      xh[q][i] = d_out[H_OFF + (size_t)(b0+q)*H_ + i];
  #pragma unroll
  for (int q = 0; q < 4; ++q) {
    float rv = 0.f;
    #pragma unroll 8
    for (int tile = 0; tile < 64; ++tile)
      rv += rvp[((size_t)(b0+q)*64 + tile)*128 + t];
    xh[q][H_ + t] = rv;
    d_out[RV_OUT_OFF + (size_t)(b0+q)*M_ + t] = rv;
  }
  __syncthreads();
  float bias = fc_b[t];
  float a0 = bias, a1 = bias, a2 = bias, a3 = bias;
  for (int j = 0; j < H_ + M_; ++j) {
    float w = fc_W[(size_t)j*OUT_ + t];
    a0 += xh[0][j]*w; a1 += xh[1][j]*w; a2 += xh[2][j]*w; a3 += xh[3][j]*w;
  }
  d_out[OUT_OFF + (size_t)(b0+0)*OUT_ + t] = sigmoidf_(a0);
  d_out[OUT_OFF + (size_t)(b0+1)*OUT_ + t] = sigmoidf_(a1);
  d_out[OUT_OFF + (size_t)(b0+2)*OUT_ + t] = sigmoidf_(a2);
  d_out[OUT_OFF + (size_t)(b0+3)*OUT_ + t] = sigmoidf_(a3);
}

extern "C" void kernel_launch(void* const* d_in, const int* in_sizes, int n_in,
                              void* d_out, int out_size, void* d_ws, size_t ws_size,
                              hipStream_t stream)
{
  const float* inp        = (const float*)d_in[0];
  const float* prev_reads = (const float*)d_in[1];
  const float* h_prev     = (const float*)d_in[2];
  const float* c_prev     = (const float*)d_in[3];
  const float* prev_rw    = (const float*)d_in[4];
  const float* prev_ww    = (const float*)d_in[5];
  const float* memory     = (const float*)d_in[6];
  const float* W_ih       = (const float*)d_in[7];
  const float* W_hh       = (const float*)d_in[8];
  const float* b_ih       = (const float*)d_in[9];
  const float* b_hh       = (const float*)d_in[10];
  const float* read_W     = (const float*)d_in[11];
  const float* read_b     = (const float*)d_in[12];
  const float* write_W    = (const float*)d_in[13];
  const float* write_b    = (const float*)d_in[14];
  const float* fc_W       = (const float*)d_in[15];
  const float* fc_b       = (const float*)d_in[16];
  float* out = (float*)d_out;
  float* ws  = (float*)d_ws;

  k1a_gemm<<<dim3(32, KSPLIT), 256, 0, stream>>>(inp, prev_reads, h_prev,
                                                 W_ih, W_hh, ws + PART_OFF);
  k1b_act<<<512, 128, 0, stream>>>(ws + PART_OFF, c_prev, b_ih, b_hh,
                                   out + H_OFF, out + C_OFF);
  k2a_gemm<<<dim3(9, KS2), 256, 0, stream>>>(out + H_OFF, read_W, write_W,
                                             ws + PART_OFF);
  k2b_post<<<B_, 256, 0, stream>>>(ws + PART_OFF, read_b, write_b, ws);
  for (int g = 0; g < B_ / GRP; ++g) {
    k3_sim<<<dim3(64, GRP), 256, 0, stream>>>(memory, ws, g*GRP);
    k4_addr<<<dim3(2, GRP), 512, 0, stream>>>(prev_rw, prev_ww, ws, out, g*GRP);
    k5_update<<<dim3(64, GRP), 256, 0, stream>>>(memory, out, ws,
                                                 ws + PART_OFF, g*GRP);
  }
  k6_fc<<<B_/4, 128, 0, stream>>>(fc_W, fc_b, out, ws + PART_OFF);
}

// Round 9
// 193.608 us; speedup vs baseline: 1.3115x; 1.3115x over previous
//
#include <hip/hip_runtime.h>
#include <math.h>

#define B_ 128
#define INPUT_ 128
#define N_ 4096
#define M_ 128
#define H_ 512
#define OUT_ 128
#define EPS_ 1e-8f

typedef float f4v __attribute__((ext_vector_type(4)));

// ---- d_out layout (float element offsets, reference return order) ----
#define OUT_OFF    0
#define RV_OUT_OFF 16384
#define H_OFF      32768
#define C_OFF      98304
#define RW_OFF     163840
#define WW_OFF     688128
#define NM_OFF     1212416

// ---- workspace layout (float element offsets) ----
#define KR_OFF     0
#define KW_OFF     16384
#define E_OFF      32768
#define A_OFF      49152
#define PRR_OFF    65536
#define PRW_OFF    66560
#define SIMR_OFF   67584
#define SIMW_OFF   591872
#define RVACC_OFF  1116160
#define PART_OFF   1132544   // k1 partials [8][2048][128]; k2 partials [8][128][576]; k5 rv partials [128][64][128]

#define KSPLIT 8
#define KPER   96
#define BO     64

#define J_FULL 524
#define J_PAD  576
#define KS2    8             // k2 split-K: 8 splits of K=64 (72 blocks, was 36)

__device__ __forceinline__ float sigmoidf_(float x){ return 1.0f/(1.0f+expf(-x)); }
__device__ __forceinline__ float softplusf_(float x){ return fmaxf(x,0.0f) + log1pf(expf(-fabsf(x))); }

// ---------------- K1a: gates GEMM, split-K tiled f32 ----------------
__global__ __launch_bounds__(256) void k1a_gemm(
    const float* __restrict__ inp, const float* __restrict__ prev_reads,
    const float* __restrict__ h_prev,
    const float* __restrict__ W_ih, const float* __restrict__ W_hh,
    float* __restrict__ part)   // [KSPLIT][2048][128]
{
  __shared__ float wt[32*68];
  __shared__ float xs[32*128];
  int t = threadIdx.x;
  int O0 = blockIdx.x * BO;
  int ks = blockIdx.y;
  int oq = t >> 5, bq = t & 31;
  float acc[8][4];
  #pragma unroll
  for (int i=0;i<8;++i)
    #pragma unroll
    for (int c=0;c<4;++c) acc[i][c]=0.f;

  for (int st = 0; st < 3; ++st) {
    int kg0 = ks*KPER + st*32;
    __syncthreads();
    {
      int o = t >> 2, kq = t & 3;
      int j = O0 + o;
      const float* wsrc; int col;
      if (kg0 < 256) { wsrc = W_ih + (size_t)j*256; col = kg0; }
      else           { wsrc = W_hh + (size_t)j*512; col = kg0 - 256; }
      float4 a0 = *(const float4*)(wsrc + col + kq*8);
      float4 a1 = *(const float4*)(wsrc + col + kq*8 + 4);
      int kk = kq*8;
      wt[(kk+0)*68+o]=a0.x; wt[(kk+1)*68+o]=a0.y; wt[(kk+2)*68+o]=a0.z; wt[(kk+3)*68+o]=a0.w;
      wt[(kk+4)*68+o]=a1.x; wt[(kk+5)*68+o]=a1.y; wt[(kk+6)*68+o]=a1.z; wt[(kk+7)*68+o]=a1.w;
    }
    {
      int b = t >> 1, kq = t & 1;
      const float* src; int col;
      if (kg0 < 128)      { src = inp        + (size_t)b*128; col = kg0; }
      else if (kg0 < 256) { src = prev_reads + (size_t)b*128; col = kg0-128; }
      else                { src = h_prev     + (size_t)b*512; col = kg0-256; }
      #pragma unroll
      for (int r = 0; r < 4; ++r) {
        float4 v = *(const float4*)(src + col + kq*16 + r*4);
        int kk = kq*16 + r*4;
        xs[(kk+0)*128+b]=v.x; xs[(kk+1)*128+b]=v.y; xs[(kk+2)*128+b]=v.z; xs[(kk+3)*128+b]=v.w;
      }
    }
    __syncthreads();
    #pragma unroll
    for (int kk = 0; kk < 32; ++kk) {
      float4 wa = *(const float4*)&wt[kk*68 + oq*8];
      float4 wb = *(const float4*)&wt[kk*68 + oq*8 + 4];
      float4 xv = *(const float4*)&xs[kk*128 + bq*4];
      float wv[8] = {wa.x,wa.y,wa.z,wa.w,wb.x,wb.y,wb.z,wb.w};
      float xx[4] = {xv.x,xv.y,xv.z,xv.w};
      #pragma unroll
      for (int i=0;i<8;++i)
        #pragma unroll
        for (int c=0;c<4;++c)
          acc[i][c] += wv[i]*xx[c];
    }
  }
  #pragma unroll
  for (int i=0;i<8;++i) {
    int j = O0 + oq*8 + i;
    float4 v = make_float4(acc[i][0],acc[i][1],acc[i][2],acc[i][3]);
    *(float4*)(part + ((size_t)ks*2048 + j)*128 + bq*4) = v;
  }
}

// ---------------- K1b: reduce split-K partials + LSTM activations ----------------
__global__ __launch_bounds__(128) void k1b_act(
    const float* __restrict__ part, const float* __restrict__ c_prev,
    const float* __restrict__ b_ih, const float* __restrict__ b_hh,
    float* __restrict__ h_out, float* __restrict__ c_out)
{
  int u = blockIdx.x;
  int b = threadIdx.x;
  float g[4];
  #pragma unroll
  for (int q=0;q<4;++q) {
    int j = q*H_ + u;
    float s = b_ih[j] + b_hh[j];
    #pragma unroll
    for (int ksp=0;ksp<KSPLIT;++ksp)
      s += part[((size_t)ksp*2048 + j)*128 + b];
    g[q] = s;
  }
  float ig = sigmoidf_(g[0]), fg = sigmoidf_(g[1]);
  float gg = tanhf(g[2]),     og = sigmoidf_(g[3]);
  float cn = fg * c_prev[(size_t)b*H_ + u] + ig*gg;
  float hn = og * tanhf(cn);
  c_out[(size_t)b*H_ + u] = cn;
  h_out[(size_t)b*H_ + u] = hn;
}

// ---------------- K2a: projection GEMM (read_W ++ write_W), split-K=8 ----------------
__global__ __launch_bounds__(256) void k2a_gemm(
    const float* __restrict__ h,
    const float* __restrict__ read_W, const float* __restrict__ write_W,
    float* __restrict__ part)  // [KS2][128][J_PAD]
{
  __shared__ float wt[32*68];
  __shared__ float xs[32*128];
  int t = threadIdx.x;
  int j0 = blockIdx.x * 64;
  int ks = blockIdx.y;
  int jq = t >> 5, bq = t & 31;
  float acc[8][4];
  #pragma unroll
  for (int i=0;i<8;++i)
    #pragma unroll
    for (int c=0;c<4;++c) acc[i][c]=0.f;

  for (int st = 0; st < 2; ++st) {      // K=64 per split: 2 stages of 32
    int k0 = ks*64 + st*32;
    __syncthreads();
    for (int e = t; e < 32*64; e += 256) {
      int kk = e >> 6, j = e & 63;
      int jc = j0 + j;
      int u = k0 + kk;
      float v = 0.f;
      if (jc < 134)          v = read_W[(size_t)u*134 + jc];
      else if (jc < J_FULL)  v = write_W[(size_t)u*390 + (jc-134)];
      wt[kk*68 + j] = v;
    }
    {
      int b = t >> 1, kq = t & 1;
      const float* src = h + (size_t)b*512 + k0 + kq*16;
      #pragma unroll
      for (int r = 0; r < 4; ++r) {
        float4 v = *(const float4*)(src + r*4);
        int kk = kq*16 + r*4;
        xs[(kk+0)*128+b]=v.x; xs[(kk+1)*128+b]=v.y; xs[(kk+2)*128+b]=v.z; xs[(kk+3)*128+b]=v.w;
      }
    }
    __syncthreads();
    #pragma unroll
    for (int kk = 0; kk < 32; ++kk) {
      float4 wa = *(const float4*)&wt[kk*68 + jq*8];
      float4 wb = *(const float4*)&wt[kk*68 + jq*8 + 4];
      float4 xv = *(const float4*)&xs[kk*128 + bq*4];
      float wv[8] = {wa.x,wa.y,wa.z,wa.w,wb.x,wb.y,wb.z,wb.w};
      float xx[4] = {xv.x,xv.y,xv.z,xv.w};
      #pragma unroll
      for (int i=0;i<8;++i)
        #pragma unroll
        for (int c=0;c<4;++c)
          acc[i][c] += wv[i]*xx[c];
    }
  }
  #pragma unroll
  for (int c=0;c<4;++c) {
    int b = bq*4 + c;
    float4 v0 = make_float4(acc[0][c],acc[1][c],acc[2][c],acc[3][c]);
    float4 v1 = make_float4(acc[4][c],acc[5][c],acc[6][c],acc[7][c]);
    *(float4*)(part + ((size_t)ks*128 + b)*J_PAD + j0 + jq*8)     = v0;
    *(float4*)(part + ((size_t)ks*128 + b)*J_PAD + j0 + jq*8 + 4) = v1;
  }
}

// ---------------- K2b: reduce partials + split_addr ----------------
__global__ __launch_bounds__(256) void k2b_post(
    const float* __restrict__ part,
    const float* __restrict__ read_b, const float* __restrict__ write_b,
    float* __restrict__ ws)
{
  int b = blockIdx.x, t = threadIdx.x;
  __shared__ float raw[J_FULL];
  __shared__ float red[128];
  for (int j = t; j < J_FULL; j += 256) {
    float s = (j < 134) ? read_b[j] : write_b[j-134];
    #pragma unroll
    for (int ks = 0; ks < KS2; ++ks)
      s += part[((size_t)ks*128 + b)*J_PAD + j];
    raw[j] = s;
  }
  __syncthreads();
  float krv = 0.f, kwv = 0.f;
  if (t < 128) {
    krv = tanhf(raw[t]);
    kwv = tanhf(raw[134+t]);
    ws[KR_OFF + b*M_ + t] = krv;
    ws[KW_OFF + b*M_ + t] = kwv;
    ws[E_OFF  + b*M_ + t] = sigmoidf_(raw[268+t]);
    ws[A_OFF  + b*M_ + t] = tanhf(raw[396+t]);
  }
  if (t < 128) red[t] = krv*krv;
  __syncthreads();
  for (int s = 64; s > 0; s >>= 1) { if (t < s) red[t] += red[t+s]; __syncthreads(); }
  float nr = sqrtf(red[0]);
  __syncthreads();
  if (t < 128) red[t] = kwv*kwv;
  __syncthreads();
  for (int s = 64; s > 0; s >>= 1) { if (t < s) red[t] += red[t+s]; __syncthreads(); }
  float nw = sqrtf(red[0]);
  if (t == 0) {
    float beta = softplusf_(raw[128]);
    float g    = sigmoidf_(raw[129]);
    float s0 = raw[130], s1 = raw[131], s2 = raw[132];
    float mx = fmaxf(s0, fmaxf(s1, s2));
    float e0 = expf(s0-mx), e1 = expf(s1-mx), e2 = expf(s2-mx);
    float es = e0+e1+e2;
    float gamma = 1.0f + softplusf_(raw[133]);
    float* pr = ws + PRR_OFF + b*8;
    pr[0]=beta; pr[1]=g; pr[2]=gamma; pr[3]=e0/es; pr[4]=e1/es; pr[5]=e2/es; pr[6]=nr;
  }
  if (t == 1) {
    float beta = softplusf_(raw[262]);
    float g    = sigmoidf_(raw[263]);
    float s0 = raw[264], s1 = raw[265], s2 = raw[266];
    float mx = fmaxf(s0, fmaxf(s1, s2));
    float e0 = expf(s0-mx), e1 = expf(s1-mx), e2 = expf(s2-mx);
    float es = e0+e1+e2;
    float gamma = 1.0f + softplusf_(raw[267]);
    float* pr = ws + PRW_OFF + b*8;
    pr[0]=beta; pr[1]=g; pr[2]=gamma; pr[3]=e0/es; pr[4]=e1/es; pr[5]=e2/es; pr[6]=nw;
  }
}

// ---------------- K3: cosine similarity pass ----------------
__global__ __launch_bounds__(256) void k3_sim(const float* __restrict__ memory,
                                              float* __restrict__ ws)
{
  int b = blockIdx.y, t = threadIdx.x;
  int n0 = blockIdx.x * 64;
  __shared__ float skr[128], skw[128];
  if (t < 128) { skr[t] = ws[KR_OFF + b*M_ + t]; skw[t] = ws[KW_OFF + b*M_ + t]; }
  __syncthreads();
  float knr = ws[PRR_OFF + b*8 + 6];
  float knw = ws[PRW_OFF + b*8 + 6];
  int wave = t >> 6, lane = t & 63, half = lane >> 5, l32 = lane & 31;
  int m0 = l32 * 4;
  #pragma unroll
  for (int i = 0; i < 8; ++i) {
    int n = n0 + i*8 + wave*2 + half;
    const float4* row = (const float4*)(memory + ((size_t)b*N_ + n)*M_);
    float4 v = row[l32];
    float dr = v.x*skr[m0] + v.y*skr[m0+1] + v.z*skr[m0+2] + v.w*skr[m0+3];
    float dw = v.x*skw[m0] + v.y*skw[m0+1] + v.z*skw[m0+2] + v.w*skw[m0+3];
    float ss = v.x*v.x + v.y*v.y + v.z*v.z + v.w*v.w;
    #pragma unroll
    for (int msk = 16; msk >= 1; msk >>= 1) {
      dr += __shfl_xor(dr, msk, 64);
      dw += __shfl_xor(dw, msk, 64);
      ss += __shfl_xor(ss, msk, 64);
    }
    if (l32 == 0) {
      float nm = sqrtf(ss);
      ws[SIMR_OFF + (size_t)b*N_ + n] = dr / (nm*knr + EPS_);
      ws[SIMW_OFF + (size_t)b*N_ + n] = dw / (nm*knw + EPS_);
    }
  }
}

// ---------------- K4: softmax + interpolate + shift + sharpen ----------------
__global__ __launch_bounds__(512) void k4_addr(
    const float* __restrict__ prev_rw, const float* __restrict__ prev_ww,
    float* __restrict__ ws, float* __restrict__ d_out)
{
  int which = blockIdx.x, b = blockIdx.y, t = threadIdx.x;
  int wid = t >> 6, lane = t & 63;
  const float* sim  = ws + (which ? SIMW_OFF : SIMR_OFF) + (size_t)b*N_;
  const float* prev = (which ? prev_ww : prev_rw) + (size_t)b*N_;
  const float* pr   = ws + (which ? PRW_OFF : PRR_OFF) + b*8;
  float* outw = d_out + (which ? WW_OFF : RW_OFF) + (size_t)b*N_;
  float beta = pr[0], g = pr[1], gamma = pr[2], s0 = pr[3], s1 = pr[4], s2 = pr[5];

  __shared__ float w[N_];
  __shared__ float redmax[8], redsum[8], redp[8];

  float vv[8];
  float mx = -1e30f;
  #pragma unroll
  for (int k = 0; k < 8; ++k) {
    int i = t + k*512;
    float v = beta * sim[i];
    vv[k] = v;
    mx = fmaxf(mx, v);
  }
  #pragma unroll
  for (int m = 1; m <= 32; m <<= 1) mx = fmaxf(mx, __shfl_xor(mx, m, 64));
  if (lane == 0) redmax[wid] = mx;
  __syncthreads();
  mx = redmax[0];
  #pragma unroll
  for (int j = 1; j < 8; ++j) mx = fmaxf(mx, redmax[j]);

  float sum = 0.f;
  #pragma unroll
  for (int k = 0; k < 8; ++k) {
    float v = __expf(vv[k] - mx);
    vv[k] = v;
    sum += v;
  }
  #pragma unroll
  for (int m = 1; m <= 32; m <<= 1) sum += __shfl_xor(sum, m, 64);
  if (lane == 0) redsum[wid] = sum;
  __syncthreads();
  sum = 0.f;
  #pragma unroll
  for (int j = 0; j < 8; ++j) sum += redsum[j];
  float inv = 1.0f / sum;

  #pragma unroll
  for (int k = 0; k < 8; ++k) {
    int i = t + k*512;
    w[i] = g * vv[k] * inv + (1.0f - g) * prev[i];
  }
  __syncthreads();

  float p[8]; float psum = 0.f;
  #pragma unroll
  for (int k = 0; k < 8; ++k) {
    int i = t + k*512;
    float wt = s0 * w[(i-1)&(N_-1)] + s1 * w[i] + s2 * w[(i+1)&(N_-1)];
    float v = __expf(gamma * __logf(wt + EPS_));
    p[k] = v; psum += v;
  }
  #pragma unroll
  for (int m = 1; m <= 32; m <<= 1) psum += __shfl_xor(psum, m, 64);
  if (lane == 0) redp[wid] = psum;
  __syncthreads();
  psum = 0.f;
  #pragma unroll
  for (int j = 0; j < 8; ++j) psum += redp[j];
  float pinv = 1.0f / psum;
  #pragma unroll
  for (int k = 0; k < 8; ++k) {
    int i = t + k*512;
    outw[i] = p[k] * pinv;
  }
}

// ---------------- K5: read_vec partials + memory erase/add (round-5 config) ----------------
__global__ __launch_bounds__(256) void k5_update(
    const float* __restrict__ memory, float* __restrict__ d_out,
    float* __restrict__ ws, float* __restrict__ rvp)
{
  int br = 127 - blockIdx.y;
  int txr = 63 - blockIdx.x;
  int t = threadIdx.x;
  int n0 = txr * 64;
  __shared__ float se[128], sa[128];
  __shared__ float rvsh[8][128];
  if (t < 128) {
    se[t] = ws[E_OFF + br*M_ + t];
    sa[t] = ws[A_OFF + br*M_ + t];
  }
  __syncthreads();
  const float* rw  = d_out + RW_OFF + (size_t)br*N_;
  const float* wwp = d_out + WW_OFF + (size_t)br*N_;
  float* nm = d_out + NM_OFF;
  int wave = t >> 6, lane = t & 63, half = lane >> 5, l32 = lane & 31;
  int slot = wave*2 + half;
  int m0 = l32 * 4;
  float rx = 0.f, ry = 0.f, rz = 0.f, rw4 = 0.f;
  #pragma unroll
  for (int i = 0; i < 8; ++i) {
    int n = n0 + i*8 + slot;
    size_t off = ((size_t)br*N_ + n) * M_;
    f4v v = __builtin_nontemporal_load((const f4v*)(memory + off) + l32);
    float rwn = rw[n], wwn = wwp[n];
    rx += rwn*v.x; ry += rwn*v.y; rz += rwn*v.z; rw4 += rwn*v.w;
    f4v o;
    o.x = v.x * (1.0f - wwn*se[m0+0]) + wwn*sa[m0+0];
    o.y = v.y * (1.0f - wwn*se[m0+1]) + wwn*sa[m0+1];
    o.z = v.z * (1.0f - wwn*se[m0+2]) + wwn*sa[m0+2];
    o.w = v.w * (1.0f - wwn*se[m0+3]) + wwn*sa[m0+3];
    __builtin_nontemporal_store(o, (f4v*)(nm + off) + l32);
  }
  rvsh[slot][m0+0] = rx;
  rvsh[slot][m0+1] = ry;
  rvsh[slot][m0+2] = rz;
  rvsh[slot][m0+3] = rw4;
  __syncthreads();
  if (t < 128) {
    float s = 0.f;
    #pragma unroll
    for (int j = 0; j < 8; ++j) s += rvsh[j][t];
    rvp[((size_t)br*64 + txr)*128 + t] = s;
  }
}

// ---------------- K6: reduce rv partials + FC head (1 batch/block, split-j) ----------------
__global__ __launch_bounds__(256) void k6_fc(
    const float* __restrict__ fc_W, const float* __restrict__ fc_b,
    float* __restrict__ d_out, const float* __restrict__ rvp)
{
  int b = blockIdx.x;
  int t = threadIdx.x & 127, hf = threadIdx.x >> 7;
  __shared__ float xh[H_ + M_];
  __shared__ float prt[2][128];
  for (int i = threadIdx.x; i < H_; i += 256)
    xh[i] = d_out[H_OFF + (size_t)b*H_ + i];
  float rv = 0.f;
  #pragma unroll 8
  for (int tile = hf*32; tile < hf*32 + 32; ++tile)
    rv += rvp[((size_t)b*64 + tile)*128 + t];
  prt[hf][t] = rv;
  __syncthreads();
  if (hf == 0) {
    rv = prt[0][t] + prt[1][t];
    xh[H_ + t] = rv;
    d_out[RV_OUT_OFF + (size_t)b*M_ + t] = rv;
  }
  __syncthreads();
  float acc = 0.f;
  for (int j = hf*320; j < hf*320 + 320; ++j)
    acc += xh[j] * fc_W[(size_t)j*OUT_ + t];
  prt[hf][t] = acc;
  __syncthreads();
  if (hf == 0)
    d_out[OUT_OFF + (size_t)b*OUT_ + t] = sigmoidf_(prt[0][t] + prt[1][t] + fc_b[t]);
}

extern "C" void kernel_launch(void* const* d_in, const int* in_sizes, int n_in,
                              void* d_out, int out_size, void* d_ws, size_t ws_size,
                              hipStream_t stream)
{
  const float* inp        = (const float*)d_in[0];
  const float* prev_reads = (const float*)d_in[1];
  const float* h_prev     = (const float*)d_in[2];
  const float* c_prev     = (const float*)d_in[3];
  const float* prev_rw    = (const float*)d_in[4];
  const float* prev_ww    = (const float*)d_in[5];
  const float* memory     = (const float*)d_in[6];
  const float* W_ih       = (const float*)d_in[7];
  const float* W_hh       = (const float*)d_in[8];
  const float* b_ih       = (const float*)d_in[9];
  const float* b_hh       = (const float*)d_in[10];
  const float* read_W     = (const float*)d_in[11];
  const float* read_b     = (const float*)d_in[12];
  const float* write_W    = (const float*)d_in[13];
  const float* write_b    = (const float*)d_in[14];
  const float* fc_W       = (const float*)d_in[15];
  const float* fc_b       = (const float*)d_in[16];
  float* out = (float*)d_out;
  float* ws  = (float*)d_ws;

  k1a_gemm<<<dim3(32, KSPLIT), 256, 0, stream>>>(inp, prev_reads, h_prev,
                                                 W_ih, W_hh, ws + PART_OFF);
  k1b_act<<<512, 128, 0, stream>>>(ws + PART_OFF, c_prev, b_ih, b_hh,
                                   out + H_OFF, out + C_OFF);
  k2a_gemm<<<dim3(9, KS2), 256, 0, stream>>>(out + H_OFF, read_W, write_W,
                                             ws + PART_OFF);
  k2b_post<<<B_, 256, 0, stream>>>(ws + PART_OFF, read_b, write_b, ws);
  k3_sim<<<dim3(64, B_), 256, 0, stream>>>(memory, ws);
  k4_addr<<<dim3(2, B_), 512, 0, stream>>>(prev_rw, prev_ww, ws, out);
  k5_update<<<dim3(64, B_), 256, 0, stream>>>(memory, out, ws, ws + PART_OFF);
  k6_fc<<<B_, 256, 0, stream>>>(fc_W, fc_b, out, ws + PART_OFF);
}